// Round 1
// baseline (1657.340 us; speedup 1.0000x reference)
//
#include <hip/hip_runtime.h>

typedef __attribute__((ext_vector_type(8))) short short8_t;
typedef __attribute__((ext_vector_type(4))) float f32x4;

#define NROWS_TOTAL 524288
#define MROWS 64
#define HSTRIDE 520   // 512 + 8 pad: 260 dwords == 4 mod 32 -> optimal b128 bank tiling, 16B aligned rows
#define NTHREADS 512

__device__ __forceinline__ unsigned short f32_to_bf16(float f) {
    union { float f; unsigned int u; } v; v.f = f;
    unsigned int r = v.u + 0x7FFFu + ((v.u >> 16) & 1u);
    return (unsigned short)(r >> 16);
}

// ws layout (bf16, transposed Wt[n][k], zero-padded):
//   W1t [512][128] @ 0        (K 105->128)
//   W2t [512][512] @ 65536
//   W3t [512][512] @ 327680
//   W4t [128][512] @ 589824   (N 100->128)
__global__ void conv_weights(const float* __restrict__ W1, const float* __restrict__ W2,
                             const float* __restrict__ W3, const float* __restrict__ W4,
                             unsigned short* __restrict__ ws) {
    int i = blockIdx.x * 256 + threadIdx.x;
    if (i < 65536) {
        int k = i & 127, n = i >> 7;
        ws[i] = f32_to_bf16(k < 105 ? W1[k * 512 + n] : 0.0f);
    } else if (i < 327680) {
        int j = i - 65536; int k = j & 511, n = j >> 9;
        ws[i] = f32_to_bf16(W2[k * 512 + n]);
    } else if (i < 589824) {
        int j = i - 327680; int k = j & 511, n = j >> 9;
        ws[i] = f32_to_bf16(W3[k * 512 + n]);
    } else if (i < 655360) {
        int j = i - 589824; int k = j & 511, n = j >> 9;
        ws[i] = f32_to_bf16(n < 100 ? W4[k * 100 + n] : 0.0f);
    }
}

__device__ __forceinline__ int clamp_bin(float sc) {
    int b = (int)floorf(sc);
    return b < 0 ? 0 : (b > 15 ? 15 : b);
}

// One MLP layer: hbuf(A, [64][HSTRIDE] bf16) x Wt(B, [512][KDIM] bf16) -> relu(.+bias) -> hbuf
template<int KDIM>
__device__ __forceinline__ void mlp_layer(unsigned short* hbuf,
                                          const unsigned short* __restrict__ Wt,
                                          const float* __restrict__ bias,
                                          int lane, int wave) {
    const int lrow = lane & 15;
    const int quad = lane >> 4;
    const int n0   = wave * 64;
    constexpr int NK = KDIM / 32;

    f32x4 zero = {0.f, 0.f, 0.f, 0.f};
    f32x4 acc[4][4];
    #pragma unroll
    for (int mt = 0; mt < 4; ++mt)
        #pragma unroll
        for (int nt = 0; nt < 4; ++nt) acc[mt][nt] = zero;

    const unsigned short* wbase  = Wt + (n0 + lrow) * KDIM + quad * 8;
    const unsigned short* abase0 = hbuf + lrow * HSTRIDE + quad * 8;

    short8_t bcur[4];
    #pragma unroll
    for (int nt = 0; nt < 4; ++nt)
        bcur[nt] = *(const short8_t*)(wbase + nt * (16 * KDIM));

    #pragma unroll 2
    for (int kc = 0; kc < NK - 1; ++kc) {
        short8_t a[4];
        #pragma unroll
        for (int mt = 0; mt < 4; ++mt)
            a[mt] = *(const short8_t*)(abase0 + mt * (16 * HSTRIDE) + kc * 32);
        short8_t bnext[4];
        #pragma unroll
        for (int nt = 0; nt < 4; ++nt)
            bnext[nt] = *(const short8_t*)(wbase + nt * (16 * KDIM) + (kc + 1) * 32);
        #pragma unroll
        for (int mt = 0; mt < 4; ++mt)
            #pragma unroll
            for (int nt = 0; nt < 4; ++nt)
                acc[mt][nt] = __builtin_amdgcn_mfma_f32_16x16x32_bf16(a[mt], bcur[nt], acc[mt][nt], 0, 0, 0);
        #pragma unroll
        for (int nt = 0; nt < 4; ++nt) bcur[nt] = bnext[nt];
    }
    {   // last K-chunk (no prefetch)
        short8_t a[4];
        #pragma unroll
        for (int mt = 0; mt < 4; ++mt)
            a[mt] = *(const short8_t*)(abase0 + mt * (16 * HSTRIDE) + (NK - 1) * 32);
        #pragma unroll
        for (int mt = 0; mt < 4; ++mt)
            #pragma unroll
            for (int nt = 0; nt < 4; ++nt)
                acc[mt][nt] = __builtin_amdgcn_mfma_f32_16x16x32_bf16(a[mt], bcur[nt], acc[mt][nt], 0, 0, 0);
    }

    __syncthreads();   // all waves finished reading hbuf for this layer

    float bv[4];
    #pragma unroll
    for (int nt = 0; nt < 4; ++nt) bv[nt] = bias[n0 + nt * 16 + lrow];

    // Epilogue: bias+relu, pair-pack adjacent cols via shfl_xor(1), b32 LDS writes.
    // C/D layout: col = lane&15, row = quad*4 + reg (verified m89/m91).
    const int odd = lane & 1;
    #pragma unroll
    for (int mt = 0; mt < 4; ++mt) {
        #pragma unroll
        for (int ntp = 0; ntp < 2; ++ntp) {
            const int t0 = ntp * 2, t1 = t0 + 1;
            const int col = n0 + t0 * 16 + odd * 16 + (lrow & ~1);
            #pragma unroll
            for (int reg = 0; reg < 4; ++reg) {
                float vA = fmaxf(acc[mt][t0][reg] + bv[t0], 0.f);
                float vB = fmaxf(acc[mt][t1][reg] + bv[t1], 0.f);
                float vm = odd ? vB : vA;   // value for my write-tile at my col
                float vs = odd ? vA : vB;   // value my xor-partner needs
                float vr = __shfl_xor(vs, 1, 64);
                unsigned int ha = f32_to_bf16(vm);
                unsigned int hb = f32_to_bf16(vr);
                unsigned int packed = odd ? (hb | (ha << 16)) : (ha | (hb << 16));
                int row = mt * 16 + quad * 4 + reg;
                *(unsigned int*)(hbuf + row * HSTRIDE + col) = packed;
            }
        }
    }
    __syncthreads();
}

__global__ void __launch_bounds__(NTHREADS, 4)
pivnet_fused(const float* __restrict__ x,
             const float* __restrict__ minv, const float* __restrict__ maxv,
             const float* __restrict__ pivots, const float* __restrict__ knnd,
             const float* __restrict__ qmean, const float* __restrict__ qstd,
             const float* __restrict__ kmean, const float* __restrict__ kstd,
             const unsigned short* __restrict__ wsw,
             const float* __restrict__ b1, const float* __restrict__ b2,
             const float* __restrict__ b3, const float* __restrict__ b4,
             float* __restrict__ out) {
    __shared__ unsigned short hbuf[MROWS * HSTRIDE];

    const int tid  = threadIdx.x;
    const int lane = tid & 63;
    const int wave = tid >> 6;
    const int row0 = blockIdx.x * MROWS;

    // ---------------- feature phase: 8 threads per row, 16 feat cols each ----------------
    {
        const int r = tid >> 3;          // 0..63 local row
        const int p = tid & 7;           // col group [p*16, p*16+16)
        const float4 xr = ((const float4*)x)[row0 + r];
        const float xa0 = xr.x, xa1 = xr.y, xa2 = xr.z, xa3 = xr.w;
        const float mn0 = minv[0], mn1 = minv[1], mn2 = minv[2], mn3 = minv[3];
        const float rg0 = maxv[0] - mn0, rg1 = maxv[1] - mn1, rg2 = maxv[2] - mn2, rg3 = maxv[3] - mn3;
        const float cd2 = (rg0 * rg0 + rg1 * rg1 + rg2 * rg2 + rg3 * rg3) * (1.0f / 256.0f);
        int bidx;
        bidx = clamp_bin((xa0 - mn0) / rg0 * 16.f);
        bidx = bidx * 16 + clamp_bin((xa1 - mn1) / rg1 * 16.f);
        bidx = bidx * 16 + clamp_bin((xa2 - mn2) / rg2 * 16.f);
        bidx = bidx * 16 + clamp_bin((xa3 - mn3) / rg3 * 16.f);
        const float* kr = knnd + (size_t)bidx * 100;

        unsigned short vals[16];
        if (p == 0) {
            vals[0] = f32_to_bf16((xa0 - qmean[0]) / qstd[0]);
            vals[1] = f32_to_bf16((xa1 - qmean[1]) / qstd[1]);
            vals[2] = f32_to_bf16((xa2 - qmean[2]) / qstd[2]);
            vals[3] = f32_to_bf16((xa3 - qmean[3]) / qstd[3]);
            const float4 pv = ((const float4*)pivots)[bidx];
            float d0 = xa0 - pv.x, d1 = xa1 - pv.y, d2 = xa2 - pv.z, d3 = xa3 - pv.w;
            vals[4] = f32_to_bf16(sqrtf((d0 * d0 + d1 * d1 + d2 * d2 + d3 * d3) / cd2));
            #pragma unroll
            for (int j = 5; j < 16; ++j) {
                int k = j - 5;
                vals[j] = f32_to_bf16((kr[k] - kmean[k]) / kstd[k]);
            }
        } else {
            #pragma unroll
            for (int j = 0; j < 16; ++j) {
                int k = p * 16 + j - 5;
                float f = 0.f;
                if (k < 100) f = (kr[k] - kmean[k]) / kstd[k];
                vals[j] = f32_to_bf16(f);
            }
        }
        unsigned int pk[8];
        #pragma unroll
        for (int j = 0; j < 8; ++j)
            pk[j] = (unsigned int)vals[2 * j] | ((unsigned int)vals[2 * j + 1] << 16);
        uint4* d4 = (uint4*)(hbuf + r * HSTRIDE + p * 16);
        d4[0] = make_uint4(pk[0], pk[1], pk[2], pk[3]);
        d4[1] = make_uint4(pk[4], pk[5], pk[6], pk[7]);
    }
    __syncthreads();

    const unsigned short* W1t = wsw;
    const unsigned short* W2t = wsw + 65536;
    const unsigned short* W3t = wsw + 327680;
    const unsigned short* W4t = wsw + 589824;

    mlp_layer<128>(hbuf, W1t, b1, lane, wave);
    mlp_layer<512>(hbuf, W2t, b2, lane, wave);
    mlp_layer<512>(hbuf, W3t, b3, lane, wave);

    // ---------------- layer 4: [64][512] x [512][100->128], write fp32 to HBM ----------------
    {
        const int lrow = lane & 15;
        const int quad = lane >> 4;
        const int col  = wave * 16 + lrow;   // waves 0..7 cover padded N=128
        f32x4 zero = {0.f, 0.f, 0.f, 0.f};
        f32x4 acc4[4];
        #pragma unroll
        for (int mt = 0; mt < 4; ++mt) acc4[mt] = zero;
        const unsigned short* wb4 = W4t + col * 512 + quad * 8;
        const unsigned short* ab0 = hbuf + lrow * HSTRIDE + quad * 8;
        short8_t bc = *(const short8_t*)wb4;
        #pragma unroll 2
        for (int kc = 0; kc < 15; ++kc) {
            short8_t a[4];
            #pragma unroll
            for (int mt = 0; mt < 4; ++mt)
                a[mt] = *(const short8_t*)(ab0 + mt * (16 * HSTRIDE) + kc * 32);
            short8_t bn = *(const short8_t*)(wb4 + (kc + 1) * 32);
            #pragma unroll
            for (int mt = 0; mt < 4; ++mt)
                acc4[mt] = __builtin_amdgcn_mfma_f32_16x16x32_bf16(a[mt], bc, acc4[mt], 0, 0, 0);
            bc = bn;
        }
        {
            short8_t a[4];
            #pragma unroll
            for (int mt = 0; mt < 4; ++mt)
                a[mt] = *(const short8_t*)(ab0 + mt * (16 * HSTRIDE) + 15 * 32);
            #pragma unroll
            for (int mt = 0; mt < 4; ++mt)
                acc4[mt] = __builtin_amdgcn_mfma_f32_16x16x32_bf16(a[mt], bc, acc4[mt], 0, 0, 0);
        }
        if (col < 100) {
            const float bb = b4[col];
            #pragma unroll
            for (int mt = 0; mt < 4; ++mt)
                #pragma unroll
                for (int reg = 0; reg < 4; ++reg) {
                    int rg = row0 + mt * 16 + quad * 4 + reg;
                    out[(size_t)rg * 100 + col] = acc4[mt][reg] + bb;
                }
        }
    }
}

extern "C" void kernel_launch(void* const* d_in, const int* in_sizes, int n_in,
                              void* d_out, int out_size, void* d_ws, size_t ws_size,
                              hipStream_t stream) {
    const float* x    = (const float*)d_in[0];
    const float* minv = (const float*)d_in[1];
    const float* maxv = (const float*)d_in[2];
    const float* piv  = (const float*)d_in[3];
    const float* knnd = (const float*)d_in[4];
    const float* qm   = (const float*)d_in[5];
    const float* qs   = (const float*)d_in[6];
    const float* km   = (const float*)d_in[7];
    const float* ks   = (const float*)d_in[8];
    const float* W1   = (const float*)d_in[9];
    const float* b1   = (const float*)d_in[10];
    const float* W2   = (const float*)d_in[11];
    const float* b2   = (const float*)d_in[12];
    const float* W3   = (const float*)d_in[13];
    const float* b3   = (const float*)d_in[14];
    const float* W4   = (const float*)d_in[15];
    const float* b4   = (const float*)d_in[16];
    float* out = (float*)d_out;
    unsigned short* wsw = (unsigned short*)d_ws;   // needs 1,310,720 B

    conv_weights<<<2560, 256, 0, stream>>>(W1, W2, W3, W4, wsw);
    pivnet_fused<<<NROWS_TOTAL / MROWS, NTHREADS, 0, stream>>>(
        x, minv, maxv, piv, knnd, qm, qs, km, ks,
        wsw, b1, b2, b3, b4, out);
}